// Round 9
// baseline (103.501 us; speedup 1.0000x reference)
//
#include <hip/hip_runtime.h>
#include <hip/hip_bf16.h>

#define NFEAT 256
#define NATOMS 4096
#define NCLAUSES 512
#define TROWS 64         // batch rows per tile (= lanes per wave)
#define NSPLIT 4         // grid = 128 tiles x 4 = 512 blocks of 512 = 2 blocks/CU
#define BLOCK 512        // 8 waves -> 4 waves/SIMD at 2 blocks/CU

// hardware transcendentals: v_exp_f32 computes 2^x
#define EXP2F(v) __builtin_amdgcn_exp2f(v)
#define RCPF(v)  __builtin_amdgcn_rcpf(v)
#define RFL(v)   __builtin_amdgcn_readfirstlane(v)

// Pre-kernel.
// blocks 0..15: pack per-atom record abf[i] = {A, B, asfloat(fid | last<<8), g}
//   e = exp(-z) = exp2(A*x + B); A = -s*B*log2e*w; B = s*B*log2e*(eta-eps)
//   last = final atom of its clause (stream sorted by clause); g = gate*leaf
//   if last else 0 -> clause boundaries live INSIDE the contiguous stream.
// block 16: CSR seg[0..512]; esum[64] = per 8-clause slot, sum of gate*leaf
//   over EMPTY clauses (each contributes exp(0)=1 per row).
__global__ void cln_pre(const float* __restrict__ w, const float* __restrict__ eta,
                        const float* __restrict__ leaf, const float* __restrict__ gate,
                        const int* __restrict__ fid, const int* __restrict__ sgn,
                        const int* __restrict__ cid,
                        float4* __restrict__ abf, int* __restrict__ seg,
                        float* __restrict__ esum) {
    __shared__ int lcid[NATOMS];            // 16 KB (block 16 only)
    __shared__ int lseg[NCLAUSES + 1];
    __shared__ float lesum[64];
    const int tid = threadIdx.x;
    const int bid = blockIdx.x;
    const float K = 144.269504088896340736f;  // B_CONST * log2(e), B=100

    if (bid < NATOMS / 256) {               // packers
        const int i = bid * 256 + tid;
        const float s = (sgn[i] == 0) ? -1.f : 1.f;
        const float a2 = -s * K * w[i];
        const float b2 =  s * K * (eta[i] - 0.01f);
        const int c = cid[i];
        const bool last = (i == NATOMS - 1) || (cid[i + 1] != c);
        const int z = fid[i] | (last ? 256 : 0);
        const float g = last ? gate[c] * leaf[c] : 0.f;
        abf[i] = make_float4(a2, b2, __int_as_float(z), g);
        return;
    }

    // ---- block 16 ----
    for (int k = tid; k < NATOMS; k += 256) lcid[k] = cid[k];
    if (tid < 64) lesum[tid] = 0.f;
    __syncthreads();
    for (int k = tid; k <= NCLAUSES; k += 256) {   // lower_bound in LDS
        int lo = 0, hi = NATOMS;
        while (lo < hi) { int mid = (lo + hi) >> 1; if (lcid[mid] < k) lo = mid + 1; else hi = mid; }
        lseg[k] = lo;
    }
    __syncthreads();
    for (int c = tid; c < NCLAUSES; c += 256)
        if (lseg[c + 1] == lseg[c])
            atomicAdd(&lesum[c >> 3], gate[c] * leaf[c]);
    __syncthreads();
    for (int k = tid; k <= NCLAUSES; k += 256) seg[k] = lseg[k];
    if (tid < 64) esum[tid] = lesum[tid];
}

// lane = batch row. Each wave interleaves TWO independent clause-streams
// (slots of 8 clauses) in one loop: 2 dependency chains per wave, per-iter
// compute ~2x L2 latency -> prefetch waits mostly covered. All control flow
// wave-uniform; chunk-4 double-buffered register prefetch per stream.
__global__ __launch_bounds__(BLOCK, 4) void cln_main(
        const float* __restrict__ x, const float4* __restrict__ abf,
        const int* __restrict__ seg, const float* __restrict__ esum,
        float* __restrict__ y) {
    __shared__ float xT[NFEAT * TROWS];   // 64 KB, rotate-swizzled

    const int tid  = threadIdx.x;
    const int wave = tid >> 6;
    const int lane = tid & 63;
    const int tile  = blockIdx.x >> 2;
    const int split = blockIdx.x & 3;
    const int row0  = tile * TROWS;

    // Stage 64 rows x 256 feats. 8 waves x 8 rows; coalesced 256B global
    // reads; LDS bank = (r+lane)&31 -> conflict-free (2-way is free).
#pragma unroll
    for (int k = 0; k < 8; ++k) {
        const int r = wave * 8 + k;
#pragma unroll
        for (int fb = 0; fb < 4; ++fb) {
            const int f = fb * 64 + lane;
            xT[f * TROWS + ((r + f) & 63)] = x[(row0 + r) * NFEAT + f];
        }
    }
    __syncthreads();

    const int slot0 = (split * 8 + wave) * 2;     // 64 slots of 8 clauses
    const int sA = seg[slot0 * 8];
    const int eA = seg[slot0 * 8 + 8];
    const int sB = seg[slot0 * 8 + 8];            // stream B = next slot
    const int eB = seg[slot0 * 8 + 16];

    float acc = esum[slot0] + esum[slot0 + 1];    // empty-clause contribution
    float pA = 1.f, pB = 1.f;

    float4 a0[4], a1[4], b0[4], b1[4];
#pragma unroll
    for (int j = 0; j < 4; ++j) {
        a0[j] = abf[min(sA + j, NATOMS - 1)];
        b0[j] = abf[min(sB + j, NATOMS - 1)];
    }

    const int itA = (eA - sA + 3) >> 2;
    const int itB = (eB - sB + 3) >> 2;
    const int nIter = max(itA, itB);
    int baseA = sA, baseB = sB;

    for (int it = 0; it < nIter; ++it) {
        // prefetch next chunk for both streams (branchless, min-clamped)
#pragma unroll
        for (int j = 0; j < 4; ++j) {
            a1[j] = abf[min(baseA + 4 + j, NATOMS - 1)];
            b1[j] = abf[min(baseB + 4 + j, NATOMS - 1)];
        }
        // issue all 8 LDS reads up front (records already in regs)
        int zA[4], zB[4];
        float xvA[4], xvB[4];
#pragma unroll
        for (int j = 0; j < 4; ++j) {
            zA[j] = RFL(__float_as_int(a0[j].z));
            zB[j] = RFL(__float_as_int(b0[j].z));
            const int fA = zA[j] & 0xFF, fB = zB[j] & 0xFF;
            xvA[j] = xT[(fA << 6) + ((lane + fA) & 63)];
            xvB[j] = xT[(fB << 6) + ((lane + fB) & 63)];
        }
        const int mA = eA - baseA, mB = eB - baseB;   // wave-uniform
#pragma unroll
        for (int j = 0; j < 4; ++j) {
            if (j < mA) {
                const float ev = EXP2F(fmaf(a0[j].x, xvA[j], a0[j].y));
                // p *= (1+e); clamp: p=inf then ev=0 gives fmaf(inf,0,inf)=NaN.
                pA = fminf(fmaf(pA, ev, pA), 1e37f);
                if (zA[j] >> 8) { acc = fmaf(a0[j].w, RCPF(pA), acc); pA = 1.f; }
            }
            if (j < mB) {
                const float ev = EXP2F(fmaf(b0[j].x, xvB[j], b0[j].y));
                pB = fminf(fmaf(pB, ev, pB), 1e37f);
                if (zB[j] >> 8) { acc = fmaf(b0[j].w, RCPF(pB), acc); pB = 1.f; }
            }
        }
#pragma unroll
        for (int j = 0; j < 4; ++j) { a0[j] = a1[j]; b0[j] = b1[j]; }
        baseA += 4; baseB += 4;
    }

    atomicAdd(&y[row0 + lane], acc);   // 32 partials per row across the grid
}

extern "C" void kernel_launch(void* const* d_in, const int* in_sizes, int n_in,
                              void* d_out, int out_size, void* d_ws, size_t ws_size,
                              hipStream_t stream) {
    const float* x    = (const float*)d_in[0];
    const float* w    = (const float*)d_in[1];
    const float* eta  = (const float*)d_in[2];
    const float* leaf = (const float*)d_in[3];
    const float* gate = (const float*)d_in[4];
    const int*   fid  = (const int*)d_in[5];
    const int*   sgn  = (const int*)d_in[6];
    const int*   cid  = (const int*)d_in[7];
    float* y = (float*)d_out;

    char* ws = (char*)d_ws;
    float4* abf  = (float4*)ws;                                      // 64 KB
    int*    seg  = (int*)(ws + NATOMS * sizeof(float4));             // 2052 B
    float*  esum = (float*)(ws + NATOMS * sizeof(float4) + 2080);    // 256 B

    const int bsz = in_sizes[0] / NFEAT;  // 8192

    hipMemsetAsync(d_out, 0, bsz * sizeof(float), stream);   // zero for atomicAdd
    cln_pre<<<NATOMS / 256 + 1, 256, 0, stream>>>(w, eta, leaf, gate, fid, sgn, cid,
                                                  abf, seg, esum);
    cln_main<<<(bsz / TROWS) * NSPLIT, BLOCK, 0, stream>>>(x, abf, seg, esum, y);
}